// Round 19
// baseline (77.579 us; speedup 1.0000x reference)
//
#include <hip/hip_runtime.h>
#include <hip/hip_bf16.h>
#include <stdint.h>

#define IN_DIM   4096
#define OUT_DIM  4096
#define RANK     256
#define MROWS    512      // 4*128 flattened batch rows
#define NNZ_CNT  262144
#define BCAP     128      // contiguous bucket capacity per row (mean 64, +8 sigma)
#define CSTRIDE  16       // cursor padded to one 64B line per row (contention fix)
#define LCAP     72       // LDS-staged entries per row (cnt>72 ~16%, global tail)

typedef __attribute__((ext_vector_type(8))) short bf16x8;
typedef __attribute__((ext_vector_type(4))) float f32x4;

// ---------------- workspace layout (bytes) ----------------
#define WS_VHB  ((size_t)0)
#define WS_USB  (WS_VHB + (size_t)RANK * IN_DIM * 2)
#define WS_XT   (WS_USB + (size_t)OUT_DIM * RANK * 2)
#define WS_T    (WS_XT  + (size_t)IN_DIM * MROWS * 2)
#define WS_CUR  (WS_T   + (size_t)MROWS * RANK * 4)
#define WS_KVB  (WS_CUR + (size_t)OUT_DIM * CSTRIDE * 4)

__device__ inline uint4 pack8(float4 a, float4 b) {
    union { __hip_bfloat16 h[8]; uint4 u; } w;
    w.h[0] = __float2bfloat16(a.x); w.h[1] = __float2bfloat16(a.y);
    w.h[2] = __float2bfloat16(a.z); w.h[3] = __float2bfloat16(a.w);
    w.h[4] = __float2bfloat16(b.x); w.h[5] = __float2bfloat16(b.y);
    w.h[6] = __float2bfloat16(b.z); w.h[7] = __float2bfloat16(b.w);
    return w.u;
}

__device__ inline float bfbits(uint32_t lo16) {
    union { uint32_t u; float f; } w; w.u = lo16 << 16; return w.f;
}

__device__ inline void fma8(float* acc, uint4 u, float v) {
    acc[0] += v * bfbits(u.x & 0xffffu);
    acc[1] += v * bfbits(u.x >> 16);
    acc[2] += v * bfbits(u.y & 0xffffu);
    acc[3] += v * bfbits(u.y >> 16);
    acc[4] += v * bfbits(u.z & 0xffffu);
    acc[5] += v * bfbits(u.z >> 16);
    acc[6] += v * bfbits(u.w & 0xffffu);
    acc[7] += v * bfbits(u.w >> 16);
}

// ---------------------------------------------------------------------------
// k1: true prerequisites only — gathers + zeroing. 512 blocks. (R18)
// ---------------------------------------------------------------------------
__global__ __launch_bounds__(256) void prep_kernel(
    const int*   __restrict__ uidx, const float* __restrict__ ucode,
    const float* __restrict__ S,
    const int*   __restrict__ vidx, const float* __restrict__ vcode,
    __hip_bfloat16* __restrict__ Vhb, __hip_bfloat16* __restrict__ Usb,
    int* __restrict__ cursor, float* __restrict__ tbuf)
{
    const int bid = blockIdx.x;
    const int t   = threadIdx.x;

    if (bid < 256) {
        int base = bid * 512;
        #pragma unroll
        for (int q = 0; q < 2; q++) {
            int sv = base + q * 256 + t;
            int cb = vidx[sv];
            const float4* vc = (const float4*)(vcode + (size_t)cb * 8);
            *(uint4*)(Vhb + (size_t)sv * 8) = pack8(vc[0], vc[1]);
        }
    } else {
        int base = (bid - 256) * 512;
        #pragma unroll
        for (int q = 0; q < 2; q++) {
            int sv = base + q * 256 + t;
            int cb = uidx[sv];
            int r0 = (sv & 31) * 8;
            const float4* uc = (const float4*)(ucode + (size_t)cb * 8);
            const float4* sp = (const float4*)(S + r0);
            float4 a = uc[0], b = uc[1], sa = sp[0], sb = sp[1];
            a.x *= sa.x; a.y *= sa.y; a.z *= sa.z; a.w *= sa.w;
            b.x *= sb.x; b.y *= sb.y; b.z *= sb.z; b.w *= sb.w;
            *(uint4*)(Usb + (size_t)sv * 8) = pack8(a, b);
        }
        cursor[(bid - 256) * 256 + t] = 0;   // 256*256 = 65536 = OUT*CSTRIDE
    }
    tbuf[bid * 256 + t] = 0.f;               // 512*256 = |t|
}

// ---------------------------------------------------------------------------
// k2: gemm1 || scatter || transpose co-scheduled (R18)
// ---------------------------------------------------------------------------
__global__ __launch_bounds__(256) void mid_kernel(
    const int* __restrict__ ridx, const float* __restrict__ rval,
    int* __restrict__ cursor, int2* __restrict__ kvb,
    const float* __restrict__ x,
    const __hip_bfloat16* __restrict__ Vhb,
    float* __restrict__ tbuf,
    __hip_bfloat16* __restrict__ xT)
{
    __shared__ __align__(16) char smem[18432];
    const int t = threadIdx.x;

    if (blockIdx.x < 256) {
        // ---- gemm1: t[512,256] += bf16(x) @ Vhb^T. split-K=8, BK=64 ----
        typedef __hip_bfloat16 bfrow[72];
        bfrow* As = (bfrow*)smem;                      // 64x72x2 = 9216 B
        bfrow* Bs = (bfrow*)(smem + 9216);

        const int bid = blockIdx.x;
        const int ks = bid & 7, nb = (bid >> 3) & 3, mb = bid >> 5;
        const int m0 = mb * 64, n0 = nb * 64, kbase = ks * 512;
        const int lane = t & 63, wave = t >> 6;
        const int wm = wave >> 1, wn = wave & 1;
        const int l15 = lane & 15, l4 = lane >> 4;
        const int srow = t >> 2, sg = t & 3;

        f32x4 acc[2][2];
        #pragma unroll
        for (int i = 0; i < 2; i++)
            #pragma unroll
            for (int j = 0; j < 2; j++) acc[i][j] = (f32x4){0.f, 0.f, 0.f, 0.f};

        for (int s = 0; s < 8; s++) {
            int k0 = kbase + s * 64;
            const float* xp = x + (size_t)(m0 + srow) * IN_DIM + k0 + sg * 16;
            *(uint4*)&As[srow][sg * 16] =
                pack8(*(const float4*)xp, *(const float4*)(xp + 4));
            *(uint4*)&As[srow][sg * 16 + 8] =
                pack8(*(const float4*)(xp + 8), *(const float4*)(xp + 12));
            const __hip_bfloat16* bp =
                Vhb + (size_t)(n0 + srow) * IN_DIM + k0 + sg * 16;
            *(uint4*)&Bs[srow][sg * 16]     = *(const uint4*)bp;
            *(uint4*)&Bs[srow][sg * 16 + 8] = *(const uint4*)(bp + 8);
            __syncthreads();
            #pragma unroll
            for (int kk = 0; kk < 2; kk++) {
                bf16x8 a[2], b[2];
                #pragma unroll
                for (int i = 0; i < 2; i++)
                    a[i] = *(const bf16x8*)&As[wm * 32 + i * 16 + l15][kk * 32 + l4 * 8];
                #pragma unroll
                for (int j = 0; j < 2; j++)
                    b[j] = *(const bf16x8*)&Bs[wn * 32 + j * 16 + l15][kk * 32 + l4 * 8];
                #pragma unroll
                for (int i = 0; i < 2; i++)
                    #pragma unroll
                    for (int j = 0; j < 2; j++)
                        acc[i][j] = __builtin_amdgcn_mfma_f32_16x16x32_bf16(
                            a[i], b[j], acc[i][j], 0, 0, 0);
            }
            __syncthreads();
        }

        #pragma unroll
        for (int i = 0; i < 2; i++)
            #pragma unroll
            for (int j = 0; j < 2; j++)
                #pragma unroll
                for (int q = 0; q < 4; q++) {
                    int row = m0 + wm * 32 + i * 16 + l4 * 4 + q;
                    int col = n0 + wn * 32 + j * 16 + l15;
                    atomicAdd(&tbuf[row * RANK + col], acc[i][j][q]);
                }
    } else if (blockIdx.x < 1280) {
        // ---- scatter: line-padded cursors, contiguous buckets ----
        int k = (blockIdx.x - 256) * 256 + t;
        int idx = ridx[k];
        int o = idx >> 12, i = idx & 4095;
        int pos = atomicAdd(&cursor[o * CSTRIDE], 1);
        if (pos < BCAP)                    // overflow ~1e-12 for this distribution
            kvb[(size_t)o * BCAP + pos] = make_int2(i, __float_as_int(rval[k]));
    } else {
        // ---- x -> xT transpose (float4 reads, uint2 stores) ----
        float (*tile)[65] = (float(*)[65])smem;        // 64x65x4 = 16640 B
        const int tb = blockIdx.x - 1280;
        const int i0 = (tb >> 3) * 64;      // 64 i-tiles
        const int m0 = (tb & 7) * 64;       // 8 m-tiles
        const int rr = t >> 4, c4 = t & 15;
        #pragma unroll
        for (int p = 0; p < 4; p++) {
            int r = p * 16 + rr;
            float4 v = *(const float4*)(x + (size_t)(m0 + r) * IN_DIM + i0 + c4 * 4);
            tile[r][c4 * 4 + 0] = v.x;
            tile[r][c4 * 4 + 1] = v.y;
            tile[r][c4 * 4 + 2] = v.z;
            tile[r][c4 * 4 + 3] = v.w;
        }
        __syncthreads();
        #pragma unroll
        for (int p = 0; p < 4; p++) {
            int i = p * 16 + rr;
            union { __hip_bfloat16 h[4]; uint2 u; } w;
            w.h[0] = __float2bfloat16(tile[c4 * 4 + 0][i]);
            w.h[1] = __float2bfloat16(tile[c4 * 4 + 1][i]);
            w.h[2] = __float2bfloat16(tile[c4 * 4 + 2][i]);
            w.h[3] = __float2bfloat16(tile[c4 * 4 + 3][i]);
            *(uint2*)(xT + (size_t)(i0 + i) * MROWS + m0 + c4 * 4) = w.u;
        }
    }
}

// ---------------------------------------------------------------------------
// k3: GEMM2 + sparse fused v4. 32m x 64o tiles, grid 1024, XCD-affinity
// swizzle. T14 async-stage: entry metadata (64 rows x 72 slots) issued as
// 9 uint4 global loads per thread AT KERNEL START (fly during phase A MFMA),
// ds_written to LDS after phase A, so phase B's only global-latency op is
// the 8-deep gather burst (~halves the dependent chain). cnt>72 tail reads
// global (proven int4-pair path). LDS 45.3KB -> 3 blocks/CU.
// ---------------------------------------------------------------------------
__global__ __launch_bounds__(256) void gemm2_sparse_kernel(
    const float* __restrict__ tbuf,
    const __hip_bfloat16* __restrict__ Usb,
    const int* __restrict__ cursor,
    const int2* __restrict__ kvb,
    const __hip_bfloat16* __restrict__ xT,
    float* __restrict__ out)
{
    __shared__ __align__(16) char smem[45312];
    typedef __hip_bfloat16 bfrowA[72];
    typedef __hip_bfloat16 bfrowB[72];
    bfrowA* As = (bfrowA*)smem;                    //  32x72x2 = 4608 B
    bfrowB* Bs = (bfrowB*)(smem + 4608);           //  64x72x2 = 9216 B
    int2 (*lkv)[LCAP] = (int2(*)[LCAP])smem;       //  64x72x8 = 36864 B (reuses As/Bs)
    float (*sacc)[33] = (float(*)[33])(smem + 36864); // 64x33x4 = 8448 B

    const int bid = blockIdx.x;
    const int mb = bid & 15, nb = bid >> 4;        // XCD-affinity mapping
    const int m0 = mb * 32, n0 = nb * 64;
    const int t = threadIdx.x;
    const int lane = t & 63, wave = t >> 6;
    const int wm = wave >> 1, wn = wave & 1;
    const int l15 = lane & 15, l4 = lane >> 4;

    // ---- T14 stage-issue: 9 uint4/thread covering lkv[64][72] (2304 int4) ----
    uint4 st[9];
    {
        const int* kvbase = (const int*)(kvb + (size_t)n0 * BCAP);
        #pragma unroll
        for (int j = 0; j < 9; j++) {
            int f = (t + j * 256) * 2;             // int2 index in [0, 4608)
            int r = f / LCAP, s = f - r * LCAP;    // row, even slot (<= 70)
            st[j] = *(const uint4*)(kvbase + ((size_t)r * BCAP + s) * 2);
        }
    }

    f32x4 acc[2];
    acc[0] = (f32x4){0.f, 0.f, 0.f, 0.f};
    acc[1] = (f32x4){0.f, 0.f, 0.f, 0.f};

    // ---- Phase A: dense MFMA (staged loads in flight underneath) ----
    {
        const int sa_row = t >> 3, sa_g = t & 7;   // A: 32 rows x 8 chunks of 8
        const int sb_row = t >> 2, sb_g = t & 3;   // B: 64 rows x 4 chunks of 16
        for (int s = 0; s < 4; s++) {
            int k0 = s * 64;
            const float* tp = tbuf + (size_t)(m0 + sa_row) * RANK + k0 + sa_g * 8;
            *(uint4*)&As[sa_row][sa_g * 8] =
                pack8(*(const float4*)tp, *(const float4*)(tp + 4));
            const __hip_bfloat16* bp =
                Usb + (size_t)(n0 + sb_row) * RANK + k0 + sb_g * 16;
            *(uint4*)&Bs[sb_row][sb_g * 16]     = *(const uint4*)bp;
            *(uint4*)&Bs[sb_row][sb_g * 16 + 8] = *(const uint4*)(bp + 8);
            __syncthreads();
            #pragma unroll
            for (int kk = 0; kk < 2; kk++) {
                bf16x8 a, b[2];
                a = *(const bf16x8*)&As[wm * 16 + l15][kk * 32 + l4 * 8];
                #pragma unroll
                for (int j = 0; j < 2; j++)
                    b[j] = *(const bf16x8*)&Bs[wn * 32 + j * 16 + l15][kk * 32 + l4 * 8];
                #pragma unroll
                for (int j = 0; j < 2; j++)
                    acc[j] = __builtin_amdgcn_mfma_f32_16x16x32_bf16(
                        a, b[j], acc[j], 0, 0, 0);
            }
            __syncthreads();   // all As/Bs reads done -> safe to overwrite w/ lkv
        }
    }

    // ---- stage-write: staged entries -> LDS (overwrites As/Bs region) ----
    {
        int2* lkvf = (int2*)smem;
        #pragma unroll
        for (int j = 0; j < 9; j++)
            *(uint4*)(lkvf + (t + j * 256) * 2) = st[j];
    }
    __syncthreads();

    // ---- Phase B: residual into sacc (entries from LDS; gathers only global) ----
    {
        const int orel = t >> 2;              // o-row within tile (64)
        const int ms   = t & 3;               // 8-m slice (32m / 4)
        const int o    = n0 + orel;
        int cnt = cursor[o * CSTRIDE]; cnt = cnt < BCAP ? cnt : BCAP;
        const int cnt2 = cnt < LCAP ? cnt : LCAP;
        const int4* lp4 = (const int4*)&lkv[orel][0];
        const int2* kp  = kvb + (size_t)o * BCAP;      // global (tail only)
        const int4* kp4 = (const int4*)kp;
        const __hip_bfloat16* xm = xT + m0 + ms * 8;

        float r[8];
        #pragma unroll
        for (int j = 0; j < 8; j++) r[j] = 0.f;

        int k = 0;
        for (; k + 8 <= cnt2; k += 8) {
            int4 e0 = lp4[(k >> 1) + 0], e1 = lp4[(k >> 1) + 1];
            int4 e2 = lp4[(k >> 1) + 2], e3 = lp4[(k >> 1) + 3];
            uint4 u0 = *(const uint4*)(xm + (size_t)e0.x * MROWS);
            uint4 u1 = *(const uint4*)(xm + (size_t)e0.z * MROWS);
            uint4 u2 = *(const uint4*)(xm + (size_t)e1.x * MROWS);
            uint4 u3 = *(const uint4*)(xm + (size_t)e1.z * MROWS);
            uint4 u4 = *(const uint4*)(xm + (size_t)e2.x * MROWS);
            uint4 u5 = *(const uint4*)(xm + (size_t)e2.z * MROWS);
            uint4 u6 = *(const uint4*)(xm + (size_t)e3.x * MROWS);
            uint4 u7 = *(const uint4*)(xm + (size_t)e3.z * MROWS);
            fma8(r, u0, __int_as_float(e0.y));
            fma8(r, u1, __int_as_float(e0.w));
            fma8(r, u2, __int_as_float(e1.y));
            fma8(r, u3, __int_as_float(e1.w));
            fma8(r, u4, __int_as_float(e2.y));
            fma8(r, u5, __int_as_float(e2.w));
            fma8(r, u6, __int_as_float(e3.y));
            fma8(r, u7, __int_as_float(e3.w));
        }
        if (k + 4 <= cnt2) {
            int4 e0 = lp4[(k >> 1) + 0], e1 = lp4[(k >> 1) + 1];
            uint4 u0 = *(const uint4*)(xm + (size_t)e0.x * MROWS);
            uint4 u1 = *(const uint4*)(xm + (size_t)e0.z * MROWS);
            uint4 u2 = *(const uint4*)(xm + (size_t)e1.x * MROWS);
            uint4 u3 = *(const uint4*)(xm + (size_t)e1.z * MROWS);
            fma8(r, u0, __int_as_float(e0.y));
            fma8(r, u1, __int_as_float(e0.w));
            fma8(r, u2, __int_as_float(e1.y));
            fma8(r, u3, __int_as_float(e1.w));
            k += 4;
        }
        for (; k < cnt2; k++) {
            int2 e = lkv[orel][k];
            uint4 u = *(const uint4*)(xm + (size_t)e.x * MROWS);
            fma8(r, u, __int_as_float(e.y));
        }
        // global tail for cnt > LCAP (~16% of rows, few entries)
        for (; k + 4 <= cnt; k += 4) {
            int4 e0 = kp4[(k >> 1) + 0], e1 = kp4[(k >> 1) + 1];
            uint4 u0 = *(const uint4*)(xm + (size_t)e0.x * MROWS);
            uint4 u1 = *(const uint4*)(xm + (size_t)e0.z * MROWS);
            uint4 u2 = *(const uint4*)(xm + (size_t)e1.x * MROWS);
            uint4 u3 = *(const uint4*)(xm + (size_t)e1.z * MROWS);
            fma8(r, u0, __int_as_float(e0.y));
            fma8(r, u1, __int_as_float(e0.w));
            fma8(r, u2, __int_as_float(e1.y));
            fma8(r, u3, __int_as_float(e1.w));
        }
        for (; k < cnt; k++) {
            int2 e = kp[k];
            uint4 u = *(const uint4*)(xm + (size_t)e.x * MROWS);
            fma8(r, u, __int_as_float(e.y));
        }

        *(float4*)&sacc[orel][ms * 8]     = make_float4(r[0], r[1], r[2], r[3]);
        *(float4*)&sacc[orel][ms * 8 + 4] = make_float4(r[4], r[5], r[6], r[7]);
    }
    __syncthreads();

    // ---- Phase C: epilogue (dense + sparse, single write) ----
    #pragma unroll
    for (int j = 0; j < 2; j++)
        #pragma unroll
        for (int q = 0; q < 4; q++) {
            int rrel = wm * 16 + l4 * 4 + q;        // m within tile (32)
            int crel = wn * 32 + j * 16 + l15;      // o within tile (64)
            out[(size_t)(m0 + rrel) * OUT_DIM + n0 + crel] =
                acc[j][q] + sacc[crel][rrel];
        }
}

// ---------------------------------------------------------------------------
extern "C" void kernel_launch(void* const* d_in, const int* in_sizes, int n_in,
                              void* d_out, int out_size, void* d_ws, size_t ws_size,
                              hipStream_t stream)
{
    const float* x    = (const float*)d_in[0];
    const int*   uidx = (const int*)  d_in[1];
    const float* ucb  = (const float*)d_in[2];
    const float* S    = (const float*)d_in[3];
    const int*   vidx = (const int*)  d_in[4];
    const float* vcb  = (const float*)d_in[5];
    const int*   ridx = (const int*)  d_in[6];
    const float* rval = (const float*)d_in[7];
    float* out = (float*)d_out;

    char* ws = (char*)d_ws;
    __hip_bfloat16* Vhb  = (__hip_bfloat16*)(ws + WS_VHB);
    __hip_bfloat16* Usb  = (__hip_bfloat16*)(ws + WS_USB);
    __hip_bfloat16* xT   = (__hip_bfloat16*)(ws + WS_XT);
    float*          tbuf = (float*)(ws + WS_T);
    int*            cur  = (int*)(ws + WS_CUR);
    int2*           kvb  = (int2*)(ws + WS_KVB);

    prep_kernel<<<dim3(512), dim3(256), 0, stream>>>(
        uidx, ucb, S, vidx, vcb, Vhb, Usb, cur, tbuf);

    mid_kernel<<<dim3(1792), dim3(256), 0, stream>>>(
        ridx, rval, cur, kvb, x, Vhb, tbuf, xT);

    gemm2_sparse_kernel<<<dim3(1024), dim3(256), 0, stream>>>(
        tbuf, Usb, cur, kvb, xT, out);
}

// Round 20
// 57.813 us; speedup vs baseline: 1.3419x; 1.3419x over previous
//
#include <hip/hip_runtime.h>
#include <hip/hip_bf16.h>
#include <stdint.h>

#define IN_DIM   4096
#define OUT_DIM  4096
#define RANK     256
#define MROWS    512      // 4*128 flattened batch rows
#define NNZ_CNT  262144
#define BCAP     128      // contiguous bucket capacity per row (mean 64, +8 sigma)
#define CSTRIDE  16       // cursor padded to one 64B line per row (contention fix)

typedef __attribute__((ext_vector_type(8))) short bf16x8;
typedef __attribute__((ext_vector_type(4))) float f32x4;

// ---------------- workspace layout (bytes) ----------------
#define WS_VHB  ((size_t)0)
#define WS_USB  (WS_VHB + (size_t)RANK * IN_DIM * 2)
#define WS_XT   (WS_USB + (size_t)OUT_DIM * RANK * 2)
#define WS_T    (WS_XT  + (size_t)IN_DIM * MROWS * 2)
#define WS_CUR  (WS_T   + (size_t)MROWS * RANK * 4)
#define WS_KVB  (WS_CUR + (size_t)OUT_DIM * CSTRIDE * 4)

__device__ inline uint4 pack8(float4 a, float4 b) {
    union { __hip_bfloat16 h[8]; uint4 u; } w;
    w.h[0] = __float2bfloat16(a.x); w.h[1] = __float2bfloat16(a.y);
    w.h[2] = __float2bfloat16(a.z); w.h[3] = __float2bfloat16(a.w);
    w.h[4] = __float2bfloat16(b.x); w.h[5] = __float2bfloat16(b.y);
    w.h[6] = __float2bfloat16(b.z); w.h[7] = __float2bfloat16(b.w);
    return w.u;
}

__device__ inline float bfbits(uint32_t lo16) {
    union { uint32_t u; float f; } w; w.u = lo16 << 16; return w.f;
}

__device__ inline void fma8(float* acc, uint4 u, float v) {
    acc[0] += v * bfbits(u.x & 0xffffu);
    acc[1] += v * bfbits(u.x >> 16);
    acc[2] += v * bfbits(u.y & 0xffffu);
    acc[3] += v * bfbits(u.y >> 16);
    acc[4] += v * bfbits(u.z & 0xffffu);
    acc[5] += v * bfbits(u.z >> 16);
    acc[6] += v * bfbits(u.w & 0xffffu);
    acc[7] += v * bfbits(u.w >> 16);
}

// ---------------------------------------------------------------------------
// k1: true prerequisites only — gathers + zeroing. 512 blocks. (R18)
// ---------------------------------------------------------------------------
__global__ __launch_bounds__(256) void prep_kernel(
    const int*   __restrict__ uidx, const float* __restrict__ ucode,
    const float* __restrict__ S,
    const int*   __restrict__ vidx, const float* __restrict__ vcode,
    __hip_bfloat16* __restrict__ Vhb, __hip_bfloat16* __restrict__ Usb,
    int* __restrict__ cursor, float* __restrict__ tbuf)
{
    const int bid = blockIdx.x;
    const int t   = threadIdx.x;

    if (bid < 256) {
        int base = bid * 512;
        #pragma unroll
        for (int q = 0; q < 2; q++) {
            int sv = base + q * 256 + t;
            int cb = vidx[sv];
            const float4* vc = (const float4*)(vcode + (size_t)cb * 8);
            *(uint4*)(Vhb + (size_t)sv * 8) = pack8(vc[0], vc[1]);
        }
    } else {
        int base = (bid - 256) * 512;
        #pragma unroll
        for (int q = 0; q < 2; q++) {
            int sv = base + q * 256 + t;
            int cb = uidx[sv];
            int r0 = (sv & 31) * 8;
            const float4* uc = (const float4*)(ucode + (size_t)cb * 8);
            const float4* sp = (const float4*)(S + r0);
            float4 a = uc[0], b = uc[1], sa = sp[0], sb = sp[1];
            a.x *= sa.x; a.y *= sa.y; a.z *= sa.z; a.w *= sa.w;
            b.x *= sb.x; b.y *= sb.y; b.z *= sb.z; b.w *= sb.w;
            *(uint4*)(Usb + (size_t)sv * 8) = pack8(a, b);
        }
        cursor[(bid - 256) * 256 + t] = 0;   // 256*256 = 65536 = OUT*CSTRIDE
    }
    tbuf[bid * 256 + t] = 0.f;               // 512*256 = |t|
}

// ---------------------------------------------------------------------------
// k2: gemm1 || scatter || transpose co-scheduled (R18)
// ---------------------------------------------------------------------------
__global__ __launch_bounds__(256) void mid_kernel(
    const int* __restrict__ ridx, const float* __restrict__ rval,
    int* __restrict__ cursor, int2* __restrict__ kvb,
    const float* __restrict__ x,
    const __hip_bfloat16* __restrict__ Vhb,
    float* __restrict__ tbuf,
    __hip_bfloat16* __restrict__ xT)
{
    __shared__ __align__(16) char smem[18432];
    const int t = threadIdx.x;

    if (blockIdx.x < 256) {
        // ---- gemm1: t[512,256] += bf16(x) @ Vhb^T. split-K=8, BK=64 ----
        typedef __hip_bfloat16 bfrow[72];
        bfrow* As = (bfrow*)smem;                      // 64x72x2 = 9216 B
        bfrow* Bs = (bfrow*)(smem + 9216);

        const int bid = blockIdx.x;
        const int ks = bid & 7, nb = (bid >> 3) & 3, mb = bid >> 5;
        const int m0 = mb * 64, n0 = nb * 64, kbase = ks * 512;
        const int lane = t & 63, wave = t >> 6;
        const int wm = wave >> 1, wn = wave & 1;
        const int l15 = lane & 15, l4 = lane >> 4;
        const int srow = t >> 2, sg = t & 3;

        f32x4 acc[2][2];
        #pragma unroll
        for (int i = 0; i < 2; i++)
            #pragma unroll
            for (int j = 0; j < 2; j++) acc[i][j] = (f32x4){0.f, 0.f, 0.f, 0.f};

        for (int s = 0; s < 8; s++) {
            int k0 = kbase + s * 64;
            const float* xp = x + (size_t)(m0 + srow) * IN_DIM + k0 + sg * 16;
            *(uint4*)&As[srow][sg * 16] =
                pack8(*(const float4*)xp, *(const float4*)(xp + 4));
            *(uint4*)&As[srow][sg * 16 + 8] =
                pack8(*(const float4*)(xp + 8), *(const float4*)(xp + 12));
            const __hip_bfloat16* bp =
                Vhb + (size_t)(n0 + srow) * IN_DIM + k0 + sg * 16;
            *(uint4*)&Bs[srow][sg * 16]     = *(const uint4*)bp;
            *(uint4*)&Bs[srow][sg * 16 + 8] = *(const uint4*)(bp + 8);
            __syncthreads();
            #pragma unroll
            for (int kk = 0; kk < 2; kk++) {
                bf16x8 a[2], b[2];
                #pragma unroll
                for (int i = 0; i < 2; i++)
                    a[i] = *(const bf16x8*)&As[wm * 32 + i * 16 + l15][kk * 32 + l4 * 8];
                #pragma unroll
                for (int j = 0; j < 2; j++)
                    b[j] = *(const bf16x8*)&Bs[wn * 32 + j * 16 + l15][kk * 32 + l4 * 8];
                #pragma unroll
                for (int i = 0; i < 2; i++)
                    #pragma unroll
                    for (int j = 0; j < 2; j++)
                        acc[i][j] = __builtin_amdgcn_mfma_f32_16x16x32_bf16(
                            a[i], b[j], acc[i][j], 0, 0, 0);
            }
            __syncthreads();
        }

        #pragma unroll
        for (int i = 0; i < 2; i++)
            #pragma unroll
            for (int j = 0; j < 2; j++)
                #pragma unroll
                for (int q = 0; q < 4; q++) {
                    int row = m0 + wm * 32 + i * 16 + l4 * 4 + q;
                    int col = n0 + wn * 32 + j * 16 + l15;
                    atomicAdd(&tbuf[row * RANK + col], acc[i][j][q]);
                }
    } else if (blockIdx.x < 1280) {
        // ---- scatter: line-padded cursors, contiguous buckets ----
        int k = (blockIdx.x - 256) * 256 + t;
        int idx = ridx[k];
        int o = idx >> 12, i = idx & 4095;
        int pos = atomicAdd(&cursor[o * CSTRIDE], 1);
        if (pos < BCAP)                    // overflow ~1e-12 for this distribution
            kvb[(size_t)o * BCAP + pos] = make_int2(i, __float_as_int(rval[k]));
    } else {
        // ---- x -> xT transpose (float4 reads, uint2 stores) ----
        float (*tile)[65] = (float(*)[65])smem;        // 64x65x4 = 16640 B
        const int tb = blockIdx.x - 1280;
        const int i0 = (tb >> 3) * 64;      // 64 i-tiles
        const int m0 = (tb & 7) * 64;       // 8 m-tiles
        const int rr = t >> 4, c4 = t & 15;
        #pragma unroll
        for (int p = 0; p < 4; p++) {
            int r = p * 16 + rr;
            float4 v = *(const float4*)(x + (size_t)(m0 + r) * IN_DIM + i0 + c4 * 4);
            tile[r][c4 * 4 + 0] = v.x;
            tile[r][c4 * 4 + 1] = v.y;
            tile[r][c4 * 4 + 2] = v.z;
            tile[r][c4 * 4 + 3] = v.w;
        }
        __syncthreads();
        #pragma unroll
        for (int p = 0; p < 4; p++) {
            int i = p * 16 + rr;
            union { __hip_bfloat16 h[4]; uint2 u; } w;
            w.h[0] = __float2bfloat16(tile[c4 * 4 + 0][i]);
            w.h[1] = __float2bfloat16(tile[c4 * 4 + 1][i]);
            w.h[2] = __float2bfloat16(tile[c4 * 4 + 2][i]);
            w.h[3] = __float2bfloat16(tile[c4 * 4 + 3][i]);
            *(uint2*)(xT + (size_t)(i0 + i) * MROWS + m0 + c4 * 4) = w.u;
        }
    }
}

// ---------------------------------------------------------------------------
// k3: GEMM2 + sparse fused v5. 64m x 64o tiles, 512 threads (8 waves),
// grid 512 (8 mb x 64 nb). XCD affinity: mb = bid & 7 -> each xT 128B line
// belongs wholly to ONE XCD (no cross-XCD line splitting; footprint 512KB
// L2-resident). Phase B: 8 lanes/row read 128B contiguous = one full L2
// line per entry (2x fewer L2 transactions than 32m tiles); wave covers 8
// rows (divergence E[max of 8]/64 = 1.25 vs 1.30 at 16 rows).
// ---------------------------------------------------------------------------
__global__ __launch_bounds__(512) void gemm2_sparse_kernel(
    const float* __restrict__ tbuf,
    const __hip_bfloat16* __restrict__ Usb,
    const int* __restrict__ cursor,
    const int2* __restrict__ kvb,
    const __hip_bfloat16* __restrict__ xT,
    float* __restrict__ out)
{
    __shared__ __align__(16) char smem[18432];
    typedef __hip_bfloat16 bfrow[72];
    bfrow* As = (bfrow*)smem;                      //  64x72x2 = 9216 B
    bfrow* Bs = (bfrow*)(smem + 9216);             //  64x72x2 = 9216 B
    float (*sacc)[65] = (float(*)[65])smem;        //  64x65x4 = 16640 B (reused)

    const int bid = blockIdx.x;
    const int mb = bid & 7, nb = bid >> 3;         // XCD-affinity mapping
    const int m0 = mb * 64, n0 = nb * 64;
    const int t = threadIdx.x;
    const int lane = t & 63, wave = t >> 6;        // 8 waves
    const int wm = wave >> 2, wn = wave & 3;       // 2x4: 32m x 16o per wave
    const int l15 = lane & 15, l4 = lane >> 4;

    f32x4 acc[2];
    acc[0] = (f32x4){0.f, 0.f, 0.f, 0.f};
    acc[1] = (f32x4){0.f, 0.f, 0.f, 0.f};

    // ---- Phase A: dense MFMA (64m x 64o, BK=64, K=256 in 4 steps) ----
    {
        const int srow = t >> 3, sg = t & 7;       // 64 rows x 8 chunks of 8
        for (int s = 0; s < 4; s++) {
            int k0 = s * 64;
            const float* tp = tbuf + (size_t)(m0 + srow) * RANK + k0 + sg * 8;
            *(uint4*)&As[srow][sg * 8] =
                pack8(*(const float4*)tp, *(const float4*)(tp + 4));
            const __hip_bfloat16* bp =
                Usb + (size_t)(n0 + srow) * RANK + k0 + sg * 8;
            *(uint4*)&Bs[srow][sg * 8] = *(const uint4*)bp;
            __syncthreads();
            #pragma unroll
            for (int kk = 0; kk < 2; kk++) {
                bf16x8 a[2], b;
                #pragma unroll
                for (int i = 0; i < 2; i++)
                    a[i] = *(const bf16x8*)&As[wm * 32 + i * 16 + l15][kk * 32 + l4 * 8];
                b = *(const bf16x8*)&Bs[wn * 16 + l15][kk * 32 + l4 * 8];
                #pragma unroll
                for (int i = 0; i < 2; i++)
                    acc[i] = __builtin_amdgcn_mfma_f32_16x16x32_bf16(
                        a[i], b, acc[i], 0, 0, 0);
            }
            __syncthreads();
        }
    }

    // ---- Phase B: residual into sacc (full-line gathers, 8-deep, int4 pairs) ----
    {
        const int orel = t >> 3;              // o-row within tile (64)
        const int ms   = t & 7;               // 8-m slice (64m / 8)
        const int o    = n0 + orel;
        int cnt = cursor[o * CSTRIDE]; cnt = cnt < BCAP ? cnt : BCAP;
        const int2* kp  = kvb + (size_t)o * BCAP;
        const int4* kp4 = (const int4*)kp;    // row base 1KB-aligned
        const __hip_bfloat16* xm = xT + m0 + ms * 8;

        float r[8];
        #pragma unroll
        for (int j = 0; j < 8; j++) r[j] = 0.f;

        int k = 0;
        for (; k + 8 <= cnt; k += 8) {
            int4 e0 = kp4[(k >> 1) + 0], e1 = kp4[(k >> 1) + 1];
            int4 e2 = kp4[(k >> 1) + 2], e3 = kp4[(k >> 1) + 3];
            uint4 u0 = *(const uint4*)(xm + (size_t)e0.x * MROWS);
            uint4 u1 = *(const uint4*)(xm + (size_t)e0.z * MROWS);
            uint4 u2 = *(const uint4*)(xm + (size_t)e1.x * MROWS);
            uint4 u3 = *(const uint4*)(xm + (size_t)e1.z * MROWS);
            uint4 u4 = *(const uint4*)(xm + (size_t)e2.x * MROWS);
            uint4 u5 = *(const uint4*)(xm + (size_t)e2.z * MROWS);
            uint4 u6 = *(const uint4*)(xm + (size_t)e3.x * MROWS);
            uint4 u7 = *(const uint4*)(xm + (size_t)e3.z * MROWS);
            fma8(r, u0, __int_as_float(e0.y));
            fma8(r, u1, __int_as_float(e0.w));
            fma8(r, u2, __int_as_float(e1.y));
            fma8(r, u3, __int_as_float(e1.w));
            fma8(r, u4, __int_as_float(e2.y));
            fma8(r, u5, __int_as_float(e2.w));
            fma8(r, u6, __int_as_float(e3.y));
            fma8(r, u7, __int_as_float(e3.w));
        }
        if (k + 4 <= cnt) {
            int4 e0 = kp4[(k >> 1) + 0], e1 = kp4[(k >> 1) + 1];
            uint4 u0 = *(const uint4*)(xm + (size_t)e0.x * MROWS);
            uint4 u1 = *(const uint4*)(xm + (size_t)e0.z * MROWS);
            uint4 u2 = *(const uint4*)(xm + (size_t)e1.x * MROWS);
            uint4 u3 = *(const uint4*)(xm + (size_t)e1.z * MROWS);
            fma8(r, u0, __int_as_float(e0.y));
            fma8(r, u1, __int_as_float(e0.w));
            fma8(r, u2, __int_as_float(e1.y));
            fma8(r, u3, __int_as_float(e1.w));
            k += 4;
        }
        for (; k < cnt; k++) {
            int2 e = kp[k];
            uint4 u = *(const uint4*)(xm + (size_t)e.x * MROWS);
            fma8(r, u, __int_as_float(e.y));
        }

        __syncthreads();   // all As/Bs reads done before sacc overwrite
        *(float4*)&sacc[orel][ms * 8]     = make_float4(r[0], r[1], r[2], r[3]);
        *(float4*)&sacc[orel][ms * 8 + 4] = make_float4(r[4], r[5], r[6], r[7]);
    }
    __syncthreads();

    // ---- Phase C: epilogue (dense + sparse, single write) ----
    #pragma unroll
    for (int i = 0; i < 2; i++)
        #pragma unroll
        for (int q = 0; q < 4; q++) {
            int rrel = wm * 32 + i * 16 + l4 * 4 + q;   // m within tile (64)
            int crel = wn * 16 + l15;                   // o within tile (64)
            out[(size_t)(m0 + rrel) * OUT_DIM + n0 + crel] =
                acc[i][q] + sacc[crel][rrel];
        }
}

// ---------------------------------------------------------------------------
extern "C" void kernel_launch(void* const* d_in, const int* in_sizes, int n_in,
                              void* d_out, int out_size, void* d_ws, size_t ws_size,
                              hipStream_t stream)
{
    const float* x    = (const float*)d_in[0];
    const int*   uidx = (const int*)  d_in[1];
    const float* ucb  = (const float*)d_in[2];
    const float* S    = (const float*)d_in[3];
    const int*   vidx = (const int*)  d_in[4];
    const float* vcb  = (const float*)d_in[5];
    const int*   ridx = (const int*)  d_in[6];
    const float* rval = (const float*)d_in[7];
    float* out = (float*)d_out;

    char* ws = (char*)d_ws;
    __hip_bfloat16* Vhb  = (__hip_bfloat16*)(ws + WS_VHB);
    __hip_bfloat16* Usb  = (__hip_bfloat16*)(ws + WS_USB);
    __hip_bfloat16* xT   = (__hip_bfloat16*)(ws + WS_XT);
    float*          tbuf = (float*)(ws + WS_T);
    int*            cur  = (int*)(ws + WS_CUR);
    int2*           kvb  = (int2*)(ws + WS_KVB);

    prep_kernel<<<dim3(512), dim3(256), 0, stream>>>(
        uidx, ucb, S, vidx, vcb, Vhb, Usb, cur, tbuf);

    mid_kernel<<<dim3(1792), dim3(256), 0, stream>>>(
        ridx, rval, cur, kvb, x, Vhb, tbuf, xT);

    gemm2_sparse_kernel<<<dim3(512), dim3(512), 0, stream>>>(
        tbuf, Usb, cur, kvb, xT, out);
}